// Round 1
// baseline (373.130 us; speedup 1.0000x reference)
//
#include <hip/hip_runtime.h>
#include <cstdint>

#define K_DIM 3072
#define B_DIM 8192
#define BM    128
#define BK    32
#define NT    64   /* 8192/128 tiles per dim */

typedef __attribute__((ext_vector_type(8))) __bf16 bf16x8;
typedef __attribute__((ext_vector_type(4))) float  f32x4;

__device__ __forceinline__ unsigned short f2bf(float f) {
    uint32_t u = __float_as_uint(f);
    u += 0x7FFFu + ((u >> 16) & 1u);   // RNE
    return (unsigned short)(u >> 16);
}

// ---------- kernel 1: bf16 copy of x + row sum-of-squares + zero sumexp ----------
__global__ __launch_bounds__(256) void prep_kernel(const float* __restrict__ x,
                                                   unsigned short* __restrict__ xb,
                                                   float* __restrict__ xn,
                                                   float* __restrict__ se)
{
    const int row = blockIdx.x;
    const int tid = threadIdx.x;
    const float4* xr = (const float4*)(x + (size_t)row * K_DIM);
    unsigned short* xbr = xb + (size_t)row * K_DIM;
    float s = 0.f;
#pragma unroll
    for (int t = 0; t < 3; ++t) {           // 768 float4 / 256 threads
        int idx = tid + t * 256;
        float4 v = xr[idx];
        s += v.x * v.x + v.y * v.y + v.z * v.z + v.w * v.w;
        ushort4 b;
        b.x = f2bf(v.x); b.y = f2bf(v.y); b.z = f2bf(v.z); b.w = f2bf(v.w);
        ((ushort4*)xbr)[idx] = b;
    }
#pragma unroll
    for (int d = 32; d > 0; d >>= 1) s += __shfl_down(s, d);
    __shared__ float red[4];
    if ((tid & 63) == 0) red[tid >> 6] = s;
    __syncthreads();
    if (tid == 0) {
        xn[row] = red[0] + red[1] + red[2] + red[3];
        se[row] = 0.f;
    }
}

// ---------- kernel 2: triangular bf16 Gram tiles + fused exp row/col sums ----------
__global__ __launch_bounds__(256) void gram_lse_kernel(const unsigned short* __restrict__ xb,
                                                       const float* __restrict__ xn,
                                                       const float* __restrict__ logvar,
                                                       float* __restrict__ se)
{
    __shared__ unsigned short lA[BM * BK];   // 8 KB
    __shared__ unsigned short lB[BM * BK];   // 8 KB

    // decode linear block id -> triangular tile (bm <= bn)
    int rem = blockIdx.x;
    int bm = 0;
    while (rem >= NT - bm) { rem -= NT - bm; ++bm; }
    const int bn = bm + rem;

    const int tid  = threadIdx.x;
    const int lane = tid & 63;
    const int wave = tid >> 6;
    const int wr = wave >> 1, wc = wave & 1;

    const size_t rowA0 = (size_t)bm * BM;
    const size_t rowB0 = (size_t)bn * BM;

    // staging addressing: each wave stages 32 rows of each tile (2 instrs x 16 rows)
    const int sRow = wave * 32 + (lane >> 2);
    const int sCol = (lane & 3) * 8;                    // bf16 elems (16 B)
    const unsigned short* gA = xb + (rowA0 + sRow) * K_DIM + sCol;
    const unsigned short* gB = xb + (rowB0 + sRow) * K_DIM + sCol;
    unsigned short* lA0 = &lA[(wave * 32) * BK];        // wave-uniform LDS base
    unsigned short* lB0 = &lB[(wave * 32) * BK];

    f32x4 acc[4][4];
#pragma unroll
    for (int i = 0; i < 4; ++i)
#pragma unroll
        for (int j = 0; j < 4; ++j) acc[i][j] = (f32x4){0.f, 0.f, 0.f, 0.f};

    const int aRow = wr * 64 + (lane & 15);
    const int bRow = wc * 64 + (lane & 15);
    const int kOff = (lane >> 4) * 8;

    for (int kt = 0; kt < K_DIM / BK; ++kt) {
        const size_t kg = (size_t)kt * BK;
        __syncthreads();   // previous iter's LDS reads done before overwrite
#pragma unroll
        for (int i = 0; i < 2; ++i) {
            __builtin_amdgcn_global_load_lds(
                (__attribute__((address_space(1))) void*)(gA + (size_t)(i * 16) * K_DIM + kg),
                (__attribute__((address_space(3))) void*)(lA0 + i * 16 * BK), 16, 0, 0);
            __builtin_amdgcn_global_load_lds(
                (__attribute__((address_space(1))) void*)(gB + (size_t)(i * 16) * K_DIM + kg),
                (__attribute__((address_space(3))) void*)(lB0 + i * 16 * BK), 16, 0, 0);
        }
        __syncthreads();   // drains vmcnt(0): LDS tiles ready

        bf16x8 aF[4], bF[4];
#pragma unroll
        for (int mi = 0; mi < 4; ++mi)
            aF[mi] = *(const bf16x8*)&lA[(aRow + mi * 16) * BK + kOff];
#pragma unroll
        for (int ni = 0; ni < 4; ++ni)
            bF[ni] = *(const bf16x8*)&lB[(bRow + ni * 16) * BK + kOff];
#pragma unroll
        for (int mi = 0; mi < 4; ++mi)
#pragma unroll
            for (int ni = 0; ni < 4; ++ni)
                acc[mi][ni] = __builtin_amdgcn_mfma_f32_16x16x32_bf16(aF[mi], bF[ni], acc[mi][ni], 0, 0, 0);
    }

    // ---- fused epilogue: exp terms + row/col partial sums ----
    const float lv  = logvar[0];
    const float var = __expf(lv) + 1e-10f;
    const float cc  = 0.5f / var;

    const int colBase = (int)rowB0 + wc * 64 + (lane & 15);
    const int rowBase = (int)rowA0 + wr * 64 + (lane >> 4) * 4;

    // row sums -> se[i], i in bm tile rows
#pragma unroll
    for (int mi = 0; mi < 4; ++mi) {
#pragma unroll
        for (int r = 0; r < 4; ++r) {
            const int i = rowBase + mi * 16 + r;
            const float xni = xn[i];
            float rs = 0.f;
#pragma unroll
            for (int ni = 0; ni < 4; ++ni) {
                const int j = colBase + ni * 16;
                const float g = acc[mi][ni][r];
                const float dist = xni + xn[j] - 2.f * g;
                rs += (i == j) ? 1.0f : __expf(-cc * fmaxf(dist, 0.f));
            }
#pragma unroll
            for (int d = 1; d < 16; d <<= 1) rs += __shfl_xor(rs, d);
            if ((lane & 15) == 0) atomicAdd(&se[i], rs);
        }
    }

    // col sums -> se[j] for off-diagonal tiles (mirror elements, i != j always)
    if (bm != bn) {
#pragma unroll
        for (int ni = 0; ni < 4; ++ni) {
            const int j = colBase + ni * 16;
            const float xnj = xn[j];
            float cs = 0.f;
#pragma unroll
            for (int mi = 0; mi < 4; ++mi) {
#pragma unroll
                for (int r = 0; r < 4; ++r) {
                    const int i = rowBase + mi * 16 + r;
                    const float g = acc[mi][ni][r];
                    cs += __expf(-cc * fmaxf(xn[i] + xnj - 2.f * g, 0.f));
                }
            }
#pragma unroll
            for (int d = 16; d < 64; d <<= 1) cs += __shfl_xor(cs, d);
            if ((lane >> 4) == 0) atomicAdd(&se[j], cs);
        }
    }
}

// ---------- kernel 3: KL scalar ----------
__global__ __launch_bounds__(256) void kl_kernel(const float* __restrict__ se,
                                                 float* __restrict__ out)
{
    const int tid = threadIdx.x;
    float s = 0.f;
    for (int i = tid; i < B_DIM; i += 256) s += logf(se[i]);
#pragma unroll
    for (int d = 32; d > 0; d >>= 1) s += __shfl_down(s, d);
    __shared__ float red[4];
    if ((tid & 63) == 0) red[tid >> 6] = s;
    __syncthreads();
    if (tid == 0) {
        const float dc = -(red[0] + red[1] + red[2] + red[3]) / (float)B_DIM;
        out[0] = (logf((float)B_DIM) + dc) / logf(2.f);
    }
}

// ---------- kernel 4: x_t = x + exp(0.5*logvar) * noise ----------
__global__ __launch_bounds__(256) void xt_kernel(const float4* __restrict__ x,
                                                 const float4* __restrict__ nz,
                                                 const float* __restrict__ logvar,
                                                 float4* __restrict__ out, int n4)
{
    const float sc = expf(0.5f * logvar[0]);
    for (int i = blockIdx.x * blockDim.x + threadIdx.x; i < n4;
         i += gridDim.x * blockDim.x) {
        float4 a = x[i], b = nz[i];
        float4 o;
        o.x = fmaf(sc, b.x, a.x);
        o.y = fmaf(sc, b.y, a.y);
        o.z = fmaf(sc, b.z, a.z);
        o.w = fmaf(sc, b.w, a.w);
        out[i] = o;
    }
}

extern "C" void kernel_launch(void* const* d_in, const int* in_sizes, int n_in,
                              void* d_out, int out_size, void* d_ws, size_t ws_size,
                              hipStream_t stream)
{
    const float* x      = (const float*)d_in[0];
    const float* noise  = (const float*)d_in[1];
    const float* logvar = (const float*)d_in[2];
    float* out = (float*)d_out;

    const size_t NEL = (size_t)B_DIM * K_DIM;   // 25165824

    // scratch carved out of d_out (overwritten by xt_kernel at the end):
    //   [0, NEL*2) bytes           : bf16 copy of x
    //   [NEL*2, NEL*2+32K) bytes   : x_norm (f32, 8192)
    //   next 32K bytes             : sumexp (f32, 8192)
    unsigned short* xb = (unsigned short*)d_out;
    float* xn = (float*)((char*)d_out + NEL * 2);
    float* se = xn + B_DIM;

    prep_kernel<<<B_DIM, 256, 0, stream>>>(x, xb, xn, se);

    const int ntri = NT * (NT + 1) / 2;   // 2080 triangular tiles
    gram_lse_kernel<<<ntri, 256, 0, stream>>>(xb, xn, logvar, se);

    kl_kernel<<<1, 256, 0, stream>>>(se, out + NEL);

    xt_kernel<<<2048, 256, 0, stream>>>((const float4*)x, (const float4*)noise,
                                        logvar, (float4*)out, (int)(NEL / 4));
}